// Round 20
// baseline (399.141 us; speedup 1.0000x reference)
//
#include <hip/hip_runtime.h>
#include <hip/hip_bf16.h>
#include <hip/hip_fp8.h>

typedef float f32x4 __attribute__((ext_vector_type(4)));
typedef short bf16x8 __attribute__((ext_vector_type(8)));

#define B_DIM 4096
#define C_DIM 1000
#define CP 1024
#define K1 2048
#define EPS 1e-6f

__device__ __forceinline__ float wsum(float v) {
#pragma unroll
  for (int o = 32; o > 0; o >>= 1) v += __shfl_xor(v, o, 64);
  return v;
}
__device__ __forceinline__ float wmax(float v) {
#pragma unroll
  for (int o = 32; o > 0; o >>= 1) v = fmaxf(v, __shfl_xor(v, o, 64));
  return v;
}

__device__ __forceinline__ void load_lds16(const void* g, void* l) {
  __builtin_amdgcn_global_load_lds(
      (const __attribute__((address_space(1))) unsigned int*)g,
      (__attribute__((address_space(3))) unsigned int*)l, 16, 0, 0);
}

// ---- merged prep v3 (R15): fp8 e4m3 pen/wsig; wsig carries x32 scale ----
__global__ void prep_all(const float* __restrict__ sig,
                         const float* __restrict__ lr,
                         const float* __restrict__ pe,
                         __hip_fp8_e4m3* __restrict__ wsig,
                         float* __restrict__ expd,
                         __hip_bfloat16* __restrict__ elc,
                         __hip_fp8_e4m3* __restrict__ pen,
                         float* __restrict__ ssb,
                         __hip_bfloat16* __restrict__ elb) {
  __shared__ float LW[4][2304];  // per wave: [32][72] padded f32
  __shared__ float AUX[4][32];   // per wave: per-row multiplier
  const int w = threadIdx.x >> 6;
  const int t = threadIdx.x & 63;
  const int unit = blockIdx.x * 4 + w;
  const bool isClass = unit < CP;
  const int c = unit;
  const int b = unit - CP;
  const bool pad = isClass && (c >= C_DIM);
  const float* src = isClass ? (sig + (size_t)c * K1) : (pe + (size_t)b * K1);

#pragma unroll
  for (int i = 0; i < 8; ++i) {
    int o = i * 256 + t * 4;
    f32x4 v = {0.f, 0.f, 0.f, 0.f};
    if (!pad) v = *(const f32x4*)(src + o);
    *(f32x4*)&LW[w][(o >> 6) * 72 + (o & 63)] = v;
  }
  __syncthreads();

  if (isClass) {
    float lv = (t < 32 && !pad) ? lr[c * 32 + t] : -3.0e38f;
    float mx = wmax(lv);
    float ev = (t < 32 && !pad) ? expf(lv - mx) : 0.f;
    float sden = wsum(ev);
    float res = pad ? 0.f : ev / sden;
    float lvn = __shfl_down(lv, 1, 64);
    if (t < 31) {
      expd[c * 32 + t] = pad ? 0.f : 1.f / (1.f + expf(-(lv - lvn)));
    } else if (t == 31) {
      expd[c * 32 + 31] = 0.f;
    }
    if (t < 32) {
      f32x4 sq = {0.f, 0.f, 0.f, 0.f};
#pragma unroll
      for (int i = 0; i < 16; ++i) {
        f32x4 v = *(const f32x4*)&LW[w][t * 72 + i * 4];
        sq += v * v;
      }
      float s = sq[0] + sq[1] + sq[2] + sq[3];
      float inv = 1.f / fmaxf(sqrtf(s), 1e-12f);
      AUX[w][t] = inv * res * 32.f;  // x32: keep fp8 values in normal range
    }
  } else {
    if (t < 32) {
      f32x4 sq = {0.f, 0.f, 0.f, 0.f}, dt = {0.f, 0.f, 0.f, 0.f};
      const int tn = (t < 31) ? t + 1 : t;
#pragma unroll
      for (int i = 0; i < 16; ++i) {
        f32x4 v = *(const f32x4*)&LW[w][t * 72 + i * 4];
        f32x4 vn = *(const f32x4*)&LW[w][tn * 72 + i * 4];
        sq += v * v;
        dt += v * vn;
      }
      float s = sq[0] + sq[1] + sq[2] + sq[3];
      float d = dt[0] + dt[1] + dt[2] + dt[3];
      float nrm = sqrtf(s);
      AUX[w][t] = 1.f / fmaxf(nrm, 1e-12f);
      float nn = __shfl_down(nrm, 1, 64);
      if (t < 31)
        ssb[(size_t)b * 32 + t] =
            (d / (fmaxf(nrm, 1e-8f) * fmaxf(nn, 1e-8f)) + 1.f) * 0.5f;
      else
        ssb[(size_t)b * 32 + 31] = 0.f;
    }
  }
  __syncthreads();

  __hip_fp8_e4m3* dst = isClass ? (wsig + (size_t)c * K1) : (pen + (size_t)b * K1);
  float es = 0.f, ls = 0.f;
#pragma unroll
  for (int l = 0; l < 32; ++l) {
    float v = LW[w][l * 72 + t];
    float m = AUX[w][l];
    dst[l * 64 + t] = __hip_fp8_e4m3(v * m);
    if (l < 16) es += v; else ls += v;
  }
  es *= (1.f / 16.f);
  ls *= (1.f / 16.f);
  float en = fmaxf(sqrtf(wsum(es * es)), 1e-12f);
  float ln2 = fmaxf(sqrtf(wsum(ls * ls)), 1e-12f);
  __hip_bfloat16* el = isClass ? (elc + (size_t)c * 128) : (elb + (size_t)b * 128);
  el[t] = __float2bfloat16(es / en);
  el[64 + t] = __float2bfloat16(ls / ln2);
}

// ---- main: R15 structure + ssum interleaved into K-loop stall windows ----
// R19 analysis: VALUBusy 33% = serial tail epilogue (~3.2k VALU insts/thread
// = 5-7us AFTER barriers drain, nothing to overlap). Fix: (1) launch_bounds
// (512,1) raises VGPR cap 128->256 (residency unchanged: LDS-bound 1 blk/CU
// = 8 waves either way) so ssum[4][4][2] fits in regs; (2) ss/ex/cm/pr get a
// dedicated LDS region (triadic drops to 3 buffers, depth-2 vmcnt(4));
// (3) one ssum chunk (m,j) per K-step, after the MFMA cluster -> VALU runs
// inside the staging stall windows (m114 wave overlap).
// Laws: VGPR cap = 256/w (R6..R9); convoys cap ~9B/cyc/CU (R12..R17);
// scattered reg-direct is transaction-bound (R18); fp8 x32-wsig safe (R15).
__global__ __launch_bounds__(512, 1)
void basin_main(const unsigned char* __restrict__ pen,
                const unsigned char* __restrict__ wsig,
                const __hip_bfloat16* __restrict__ elb,
                const __hip_bfloat16* __restrict__ elc,
                const float* __restrict__ ssb,
                const float* __restrict__ expd,
                const float* __restrict__ cm,
                const float* __restrict__ proto,
                float* __restrict__ out) {
  // LDS map: buf0 0..32K, buf1 32K..64K, buf2 64K..96K,
  //          ss 98304(+18432), ex 116736(+18432), cm 135168, pr 135680
  __shared__ __align__(16) char smem[136192];
  const int t = threadIdx.x;
  const int lane = t & 63;
  const int w = t >> 6;               // 0..7
  const int wm = w >> 2, wn = w & 3;  // 2M x 4N waves, each 64x32
  const int brow = blockIdx.x * 128;
  const int bcol = blockIdx.y * 128;
  const int srow = t >> 3;      // 0..63 (row within 64-row group)
  const int schunk = t & 7;     // 16B chunk in row
  const int sel = ((schunk ^ (srow & 7)) << 4);  // byte offset in 128B row
  const int l15 = lane & 15;
  const int gq = lane >> 4;     // 0..3

  const int rowA = (wm * 64 + l15) << 7;  // byte offset of A row (128B rows)
  const int rowB = (wn * 32 + l15) << 7;  // B row (before +16384)
  int xg8[4];
#pragma unroll
  for (int kk = 0; kk < 4; ++kk)
    xg8[kk] = ((((kk * 2 + (gq >> 1)) ^ (l15 & 7)) << 4) | ((gq & 1) << 3));
  int xgh[2];
#pragma unroll
  for (int kk = 0; kk < 2; ++kk) xgh[kk] = (((kk * 4 + gq) ^ (l15 & 7)) << 4);

  float* ss_l = (float*)(smem + 98304);   // [128][36] padded
  float* ex_l = (float*)(smem + 116736);  // [128][36]
  float* cm_l = (float*)(smem + 135168);  // [128]
  float* pr_l = (float*)(smem + 135680);  // [128]
  const int col0 = wn * 32 + l15;
  const int row0 = wm * 64 + (gq << 2);

  f32x4 acc1[4][2] = {};
  f32x4 acc2[4][2] = {};
  float ssum[4][4][2];  // [m][j][n], filled one (m,j) chunk per K-step

#define STAGE_T(kt, BI)                                                                   \
  do {                                                                                    \
    _Pragma("unroll") for (int i = 0; i < 2; ++i) {                                       \
      load_lds16(pen + (size_t)(brow + i * 64 + srow) * K1 + (kt) * 128 + sel,            \
                 smem + (BI) * 32768 + i * 8192 + t * 16);                                \
      load_lds16(wsig + (size_t)(bcol + i * 64 + srow) * K1 + (kt) * 128 + sel,           \
                 smem + (BI) * 32768 + 16384 + i * 8192 + t * 16);                        \
    }                                                                                     \
  } while (0)

#define STAGE_H(s, BI)                                                                    \
  do {                                                                                    \
    _Pragma("unroll") for (int i = 0; i < 2; ++i) {                                       \
      load_lds16(elb + (size_t)(brow + i * 64 + srow) * 128 + (s) * 64 + (sel >> 1),      \
                 smem + (BI) * 32768 + i * 8192 + t * 16);                                \
      load_lds16(elc + (size_t)(bcol + i * 64 + srow) * 128 + (s) * 64 + (sel >> 1),      \
                 smem + (BI) * 32768 + 16384 + i * 8192 + t * 16);                        \
    }                                                                                     \
  } while (0)

#define COMPUTE(ACC, BI)                                                                  \
  do {                                                                                    \
    _Pragma("unroll") for (int kk = 0; kk < 4; ++kk) {                                    \
      long af[4], bg[2];                                                                  \
      _Pragma("unroll") for (int m = 0; m < 4; ++m)                                       \
          af[m] = *(const long*)(smem + (BI) * 32768 + rowA + m * 2048 + xg8[kk]);        \
      _Pragma("unroll") for (int n = 0; n < 2; ++n)                                       \
          bg[n] = *(const long*)(smem + (BI) * 32768 + 16384 + rowB + n * 2048 + xg8[kk]); \
      _Pragma("unroll") for (int m = 0; m < 4; ++m)                                       \
        _Pragma("unroll") for (int n = 0; n < 2; ++n)                                     \
          ACC[m][n] = __builtin_amdgcn_mfma_f32_16x16x32_fp8_fp8(af[m], bg[n], ACC[m][n], 0, 0, 0); \
    }                                                                                     \
  } while (0)

#define COMPUTE_H(ACC, BI)                                                                \
  do {                                                                                    \
    _Pragma("unroll") for (int kk = 0; kk < 2; ++kk) {                                    \
      bf16x8 af[4], bg[2];                                                                \
      _Pragma("unroll") for (int m = 0; m < 4; ++m)                                       \
          af[m] = *(const bf16x8*)(smem + (BI) * 32768 + rowA + m * 2048 + xgh[kk]);      \
      _Pragma("unroll") for (int n = 0; n < 2; ++n)                                       \
          bg[n] = *(const bf16x8*)(smem + (BI) * 32768 + 16384 + rowB + n * 2048 + xgh[kk]); \
      _Pragma("unroll") for (int m = 0; m < 4; ++m)                                       \
        _Pragma("unroll") for (int n = 0; n < 2; ++n)                                     \
          ACC[m][n] = __builtin_amdgcn_mfma_f32_16x16x32_bf16(af[m], bg[n], ACC[m][n], 0, 0, 0); \
    }                                                                                     \
  } while (0)

// one (m,j) = (KT>>2, KT&3) chunk of the |ss-exp| reduction; KT is a literal
#define SSUM_CHUNK(KT)                                                                    \
  do {                                                                                    \
    const int _row = row0 + ((KT) >> 2) * 16 + ((KT) & 3);                                \
    f32x4 s0 = {0.f, 0.f, 0.f, 0.f}, s1 = {0.f, 0.f, 0.f, 0.f};                           \
    _Pragma("unroll") for (int l4 = 0; l4 < 32; l4 += 4) {                                \
      f32x4 sv = *(const f32x4*)&ss_l[_row * 36 + l4];                                    \
      f32x4 e0 = *(const f32x4*)&ex_l[col0 * 36 + l4];                                    \
      f32x4 e1 = *(const f32x4*)&ex_l[(col0 + 16) * 36 + l4];                             \
      _Pragma("unroll") for (int e = 0; e < 4; ++e) {                                     \
        s0[e] += fabsf(sv[e] - e0[e]);                                                    \
        s1[e] += fabsf(sv[e] - e1[e]);                                                    \
      }                                                                                   \
    }                                                                                     \
    ssum[(KT) >> 2][(KT) & 3][0] = s0[0] + s0[1] + s0[2] + s0[3];                         \
    ssum[(KT) >> 2][(KT) & 3][1] = s1[0] + s1[1] + s1[2] + s1[3];                         \
  } while (0)

#define VMW(N) asm volatile("s_waitcnt vmcnt(" #N ")" ::: "memory")
#define BAR()                    \
  __builtin_amdgcn_s_barrier();  \
  __builtin_amdgcn_sched_barrier(0)

  // ---- prologue: stage 0,1 + epilogue arrays; one full drain ----
  STAGE_T(0, 0);
  STAGE_T(1, 1);
#pragma unroll
  for (int i = 0; i < 8; ++i) {
    int idx = i * 512 + t;
    int r = idx >> 5, l = idx & 31;
    ss_l[r * 36 + l] = ssb[(size_t)(brow + r) * 32 + l];
    ex_l[r * 36 + l] = expd[(size_t)(bcol + r) * 32 + l];
  }
  if (t < 128) cm_l[t] = cm[brow + t];
  else if (t < 256) pr_l[t - 128] = (bcol + t - 128 < C_DIM) ? proto[bcol + t - 128] : 0.f;
  __syncthreads();  // drains vmcnt (stages 0,1) + lgkm (ds_writes) + barrier

  // ---- triadic GEMM: 16 steps BK=128 fp8, 3 buffers depth-2, ssum hidden ----
#pragma unroll
  for (int kt = 0; kt < 14; ++kt) {
    VMW(4);  // stage kt landed (kt+1 still in flight)
    BAR();   // all waves done reading buf (kt-1)%3 == (kt+2)%3
    STAGE_T(kt + 2, (kt + 2) % 3);
    COMPUTE(acc1, kt % 3);
    SSUM_CHUNK(kt);
  }
  // step 14: stage hier H0 into buf1 (last read at step 13; BAR proves done)
  VMW(4); BAR();
  STAGE_H(0, 1);
  COMPUTE(acc1, 2);
  SSUM_CHUNK(14);
  // step 15: stage H1 into buf2 (freed by this BAR)
  VMW(4); BAR();
  STAGE_H(1, 2);
  COMPUTE(acc1, 0);
  SSUM_CHUNK(15);

  // ---- hier GEMM (bf16): 2 steps of BK=64 on buffers 1,2 ----
  VMW(4); BAR();
  COMPUTE_H(acc2, 1);
  VMW(0); BAR();
  COMPUTE_H(acc2, 2);

  // ---- epilogue: pure combine (ssum precomputed) ----
#pragma unroll
  for (int m = 0; m < 4; ++m) {
#pragma unroll
    for (int j = 0; j < 4; ++j) {
      int rloc = row0 + m * 16 + j;
      float cmv = cm_l[rloc];
#pragma unroll
      for (int n = 0; n < 2; ++n) {
        int cloc = col0 + n * 16;
        int cg = bcol + cloc;
        // acc1 carries the x32 wsig scale: triadic = 0.5 + 0.5*acc/32
        float tria = fminf(fmaxf(0.5f + acc1[m][n][j] * 0.015625f, EPS), 1.0f);
        float hier = fminf(fmaxf(0.5f + 0.25f * acc2[m][n][j], EPS), 1.0f);
        float sc = fminf(fmaxf(1.0f - ssum[m][j][n] * (1.0f / 31.0f), EPS), 1.0f);
        float d = cmv - pr_l[cloc];
        float cc = __expf(d * d * -10.0f) + 1e-8f;
        cc = fminf(fmaxf(cc, EPS), 1.0f);
        float p = tria * sc * cc * hier;
        if (cg < C_DIM)
          out[(size_t)(brow + rloc) * C_DIM + cg] = sqrtf(sqrtf(p));
      }
    }
  }
}

extern "C" void kernel_launch(void* const* d_in, const int* in_sizes, int n_in,
                              void* d_out, int out_size, void* d_ws, size_t ws_size,
                              hipStream_t stream) {
  (void)in_sizes; (void)n_in; (void)out_size; (void)ws_size;
  const float* pe = (const float*)d_in[0];     // B x L x F
  const float* cm = (const float*)d_in[1];     // B
  const float* sig = (const float*)d_in[2];    // C x L x F
  const float* proto = (const float*)d_in[3];  // C
  const float* lr = (const float*)d_in[4];     // C x L
  float* out = (float*)d_out;
  char* ws = (char*)d_ws;

  __hip_fp8_e4m3* wsig = (__hip_fp8_e4m3*)(ws);               // CP*2048 = 2 MiB
  __hip_fp8_e4m3* pen = (__hip_fp8_e4m3*)(ws + 2097152);      // B*2048  = 8 MiB
  __hip_bfloat16* elb = (__hip_bfloat16*)(ws + 10485760);     // B*128*2 = 1 MiB
  __hip_bfloat16* elc = (__hip_bfloat16*)(ws + 11534336);     // CP*128*2 = 256 KiB
  float* ssb = (float*)(ws + 11796480);                       // B*32*4  = 512 KiB
  float* expd = (float*)(ws + 12320768);                      // CP*32*4 = 128 KiB

  prep_all<<<(CP + B_DIM) / 4, 256, 0, stream>>>(sig, lr, pe, wsig, expd, elc, pen, ssb, elb);
  dim3 grid(B_DIM / 128, CP / 128);
  basin_main<<<grid, 512, 0, stream>>>((const unsigned char*)pen, (const unsigned char*)wsig,
                                       elb, elc, ssb, expd, cm, proto, out);
}

// Round 21
// 56.577 us; speedup vs baseline: 7.0548x; 7.0548x over previous
//
#include <hip/hip_runtime.h>
#include <hip/hip_bf16.h>
#include <hip/hip_fp8.h>

typedef float f32x4 __attribute__((ext_vector_type(4)));
typedef short bf16x8 __attribute__((ext_vector_type(8)));

#define B_DIM 4096
#define C_DIM 1000
#define CP 1024
#define K1 2048
#define EPS 1e-6f

__device__ __forceinline__ float wsum(float v) {
#pragma unroll
  for (int o = 32; o > 0; o >>= 1) v += __shfl_xor(v, o, 64);
  return v;
}
__device__ __forceinline__ float wmax(float v) {
#pragma unroll
  for (int o = 32; o > 0; o >>= 1) v = fmaxf(v, __shfl_xor(v, o, 64));
  return v;
}

__device__ __forceinline__ void load_lds16(const void* g, void* l) {
  __builtin_amdgcn_global_load_lds(
      (const __attribute__((address_space(1))) unsigned int*)g,
      (__attribute__((address_space(3))) unsigned int*)l, 16, 0, 0);
}

// ---- merged prep v3 (R15): fp8 e4m3 pen/wsig; wsig carries x32 scale ----
__global__ void prep_all(const float* __restrict__ sig,
                         const float* __restrict__ lr,
                         const float* __restrict__ pe,
                         __hip_fp8_e4m3* __restrict__ wsig,
                         float* __restrict__ expd,
                         __hip_bfloat16* __restrict__ elc,
                         __hip_fp8_e4m3* __restrict__ pen,
                         float* __restrict__ ssb,
                         __hip_bfloat16* __restrict__ elb) {
  __shared__ float LW[4][2304];  // per wave: [32][72] padded f32
  __shared__ float AUX[4][32];   // per wave: per-row multiplier
  const int w = threadIdx.x >> 6;
  const int t = threadIdx.x & 63;
  const int unit = blockIdx.x * 4 + w;
  const bool isClass = unit < CP;
  const int c = unit;
  const int b = unit - CP;
  const bool pad = isClass && (c >= C_DIM);
  const float* src = isClass ? (sig + (size_t)c * K1) : (pe + (size_t)b * K1);

#pragma unroll
  for (int i = 0; i < 8; ++i) {
    int o = i * 256 + t * 4;
    f32x4 v = {0.f, 0.f, 0.f, 0.f};
    if (!pad) v = *(const f32x4*)(src + o);
    *(f32x4*)&LW[w][(o >> 6) * 72 + (o & 63)] = v;
  }
  __syncthreads();

  if (isClass) {
    float lv = (t < 32 && !pad) ? lr[c * 32 + t] : -3.0e38f;
    float mx = wmax(lv);
    float ev = (t < 32 && !pad) ? expf(lv - mx) : 0.f;
    float sden = wsum(ev);
    float res = pad ? 0.f : ev / sden;
    float lvn = __shfl_down(lv, 1, 64);
    if (t < 31) {
      expd[c * 32 + t] = pad ? 0.f : 1.f / (1.f + expf(-(lv - lvn)));
    } else if (t == 31) {
      expd[c * 32 + 31] = 0.f;
    }
    if (t < 32) {
      f32x4 sq = {0.f, 0.f, 0.f, 0.f};
#pragma unroll
      for (int i = 0; i < 16; ++i) {
        f32x4 v = *(const f32x4*)&LW[w][t * 72 + i * 4];
        sq += v * v;
      }
      float s = sq[0] + sq[1] + sq[2] + sq[3];
      float inv = 1.f / fmaxf(sqrtf(s), 1e-12f);
      AUX[w][t] = inv * res * 32.f;  // x32: keep fp8 values in normal range
    }
  } else {
    if (t < 32) {
      f32x4 sq = {0.f, 0.f, 0.f, 0.f}, dt = {0.f, 0.f, 0.f, 0.f};
      const int tn = (t < 31) ? t + 1 : t;
#pragma unroll
      for (int i = 0; i < 16; ++i) {
        f32x4 v = *(const f32x4*)&LW[w][t * 72 + i * 4];
        f32x4 vn = *(const f32x4*)&LW[w][tn * 72 + i * 4];
        sq += v * v;
        dt += v * vn;
      }
      float s = sq[0] + sq[1] + sq[2] + sq[3];
      float d = dt[0] + dt[1] + dt[2] + dt[3];
      float nrm = sqrtf(s);
      AUX[w][t] = 1.f / fmaxf(nrm, 1e-12f);
      float nn = __shfl_down(nrm, 1, 64);
      if (t < 31)
        ssb[(size_t)b * 32 + t] =
            (d / (fmaxf(nrm, 1e-8f) * fmaxf(nn, 1e-8f)) + 1.f) * 0.5f;
      else
        ssb[(size_t)b * 32 + 31] = 0.f;
    }
  }
  __syncthreads();

  __hip_fp8_e4m3* dst = isClass ? (wsig + (size_t)c * K1) : (pen + (size_t)b * K1);
  float es = 0.f, ls = 0.f;
#pragma unroll
  for (int l = 0; l < 32; ++l) {
    float v = LW[w][l * 72 + t];
    float m = AUX[w][l];
    dst[l * 64 + t] = __hip_fp8_e4m3(v * m);
    if (l < 16) es += v; else ls += v;
  }
  es *= (1.f / 16.f);
  ls *= (1.f / 16.f);
  float en = fmaxf(sqrtf(wsum(es * es)), 1e-12f);
  float ln2 = fmaxf(sqrtf(wsum(ls * ls)), 1e-12f);
  __hip_bfloat16* el = isClass ? (elc + (size_t)c * 128) : (elb + (size_t)b * 128);
  el[t] = __float2bfloat16(es / en);
  el[64 + t] = __float2bfloat16(ls / ln2);
}

// ---- main: 128x128 tile, 8 waves (64x32), fp8 triadic BK=128, depth-3 ----
// FINAL (R15/R19 configuration, session best: main 45.2us, total 56.7us,
// reproduced twice). Session laws:
// (1) VGPR: grant is effectively pinned at 128 for 512-thr blocks; declared
//     w=4 halves it to 64 => spills => 8x HBM traffic (R6/R7/R9); extra reg
//     demand at 128 (R20 ssum-in-regs) => spills => 14x traffic. w=2, stay
//     under 128 live regs.
// (2) Staging convoys cap ~9 B/cyc/CU per workgroup stream regardless of
//     depth/bytes/blocks (R12..R17).
// (3) Register-direct scattered loads are transaction-bound, 1.8x worse (R18).
// (4) fp8 staging (x32-scaled wsig) accuracy-safe: absmax 3.9e-3 vs 15.3e-3.
__global__ __launch_bounds__(512, 2)
void basin_main(const unsigned char* __restrict__ pen,
                const unsigned char* __restrict__ wsig,
                const __hip_bfloat16* __restrict__ elb,
                const __hip_bfloat16* __restrict__ elc,
                const float* __restrict__ ssb,
                const float* __restrict__ expd,
                const float* __restrict__ cm,
                const float* __restrict__ proto,
                float* __restrict__ out) {
  __shared__ __align__(16) char smem[131072];  // 4 x (A 16KB + B 16KB)
  const int t = threadIdx.x;
  const int lane = t & 63;
  const int w = t >> 6;               // 0..7
  const int wm = w >> 2, wn = w & 3;  // 2M x 4N waves, each 64x32
  const int brow = blockIdx.x * 128;
  const int bcol = blockIdx.y * 128;
  const int srow = t >> 3;      // 0..63 (row within 64-row group)
  const int schunk = t & 7;     // 16B chunk in row
  const int sel = ((schunk ^ (srow & 7)) << 4);  // byte offset in 128B row
  const int l15 = lane & 15;
  const int gq = lane >> 4;     // 0..3

  const int rowA = (wm * 64 + l15) << 7;  // byte offset of A row (128B rows)
  const int rowB = (wn * 32 + l15) << 7;  // B row (before +16384)
  // fp8 read: lane wants global 8B-granule g8 = kk*4+gq of its row; LDS
  // 16B-chunk = (g8>>1)^(row&7), low half (g8&1).
  int xg8[4];
#pragma unroll
  for (int kk = 0; kk < 4; ++kk)
    xg8[kk] = ((((kk * 2 + (gq >> 1)) ^ (l15 & 7)) << 4) | ((gq & 1) << 3));
  // bf16 hier read (BK=64, 16B frags): chunk = (kk*4+gq)^(row&7)
  int xgh[2];
#pragma unroll
  for (int kk = 0; kk < 2; ++kk) xgh[kk] = (((kk * 4 + gq) ^ (l15 & 7)) << 4);

  f32x4 acc1[4][2] = {};
  f32x4 acc2[4][2] = {};

// BI literal. Buffer at BI*32768: A 16KB then B 16KB.
#define STAGE_T(kt, BI)                                                                   \
  do {                                                                                    \
    _Pragma("unroll") for (int i = 0; i < 2; ++i) {                                       \
      load_lds16(pen + (size_t)(brow + i * 64 + srow) * K1 + (kt) * 128 + sel,            \
                 smem + (BI) * 32768 + i * 8192 + t * 16);                                \
      load_lds16(wsig + (size_t)(bcol + i * 64 + srow) * K1 + (kt) * 128 + sel,           \
                 smem + (BI) * 32768 + 16384 + i * 8192 + t * 16);                        \
    }                                                                                     \
  } while (0)

#define STAGE_H(s, BI)                                                                    \
  do {                                                                                    \
    _Pragma("unroll") for (int i = 0; i < 2; ++i) {                                       \
      load_lds16(elb + (size_t)(brow + i * 64 + srow) * 128 + (s) * 64 + (sel >> 1),      \
                 smem + (BI) * 32768 + i * 8192 + t * 16);                                \
      load_lds16(elc + (size_t)(bcol + i * 64 + srow) * 128 + (s) * 64 + (sel >> 1),      \
                 smem + (BI) * 32768 + 16384 + i * 8192 + t * 16);                        \
    }                                                                                     \
  } while (0)

// fp8 step: 4 kk x (4 A + 2 B ds_read_b64, 8 MFMA) = 24 ds + 32 MFMA (K=128)
#define COMPUTE(ACC, BI)                                                                  \
  do {                                                                                    \
    _Pragma("unroll") for (int kk = 0; kk < 4; ++kk) {                                    \
      long af[4], bg[2];                                                                  \
      _Pragma("unroll") for (int m = 0; m < 4; ++m)                                       \
          af[m] = *(const long*)(smem + (BI) * 32768 + rowA + m * 2048 + xg8[kk]);        \
      _Pragma("unroll") for (int n = 0; n < 2; ++n)                                       \
          bg[n] = *(const long*)(smem + (BI) * 32768 + 16384 + rowB + n * 2048 + xg8[kk]); \
      _Pragma("unroll") for (int m = 0; m < 4; ++m)                                       \
        _Pragma("unroll") for (int n = 0; n < 2; ++n)                                     \
          ACC[m][n] = __builtin_amdgcn_mfma_f32_16x16x32_fp8_fp8(af[m], bg[n], ACC[m][n], 0, 0, 0); \
    }                                                                                     \
  } while (0)

// bf16 hier step (BK=64): 2 kk x (6 ds_read_b128, 8 MFMA)
#define COMPUTE_H(ACC, BI)                                                                \
  do {                                                                                    \
    _Pragma("unroll") for (int kk = 0; kk < 2; ++kk) {                                    \
      bf16x8 af[4], bg[2];                                                                \
      _Pragma("unroll") for (int m = 0; m < 4; ++m)                                       \
          af[m] = *(const bf16x8*)(smem + (BI) * 32768 + rowA + m * 2048 + xgh[kk]);      \
      _Pragma("unroll") for (int n = 0; n < 2; ++n)                                       \
          bg[n] = *(const bf16x8*)(smem + (BI) * 32768 + 16384 + rowB + n * 2048 + xgh[kk]); \
      _Pragma("unroll") for (int m = 0; m < 4; ++m)                                       \
        _Pragma("unroll") for (int n = 0; n < 2; ++n)                                     \
          ACC[m][n] = __builtin_amdgcn_mfma_f32_16x16x32_bf16(af[m], bg[n], ACC[m][n], 0, 0, 0); \
    }                                                                                     \
  } while (0)

#define VMW(N) asm volatile("s_waitcnt vmcnt(" #N ")" ::: "memory")
#define BAR()                    \
  __builtin_amdgcn_s_barrier();  \
  __builtin_amdgcn_sched_barrier(0)

// steady-state: 3 stages (12 insts) in flight; wait oldest (stage kt)
#define KSTEP_S(kt, BI, NXT)                                                              \
  do {                                                                                    \
    VMW(8);                                                                               \
    BAR();                                                                                \
    STAGE_T((kt) + 3, NXT);                                                               \
    COMPUTE(acc1, BI);                                                                    \
  } while (0)

  // ---- triadic GEMM: K=2048, 16 steps of BK=128 fp8, depth-3 pipeline ----
  STAGE_T(0, 0);
  STAGE_T(1, 1);
  STAGE_T(2, 2);
  for (int kt = 0; kt < 12; kt += 4) {  // steps 0..11, issue stages 3..14
    KSTEP_S(kt, 0, 3);
    KSTEP_S(kt + 1, 1, 0);
    KSTEP_S(kt + 2, 2, 1);
    KSTEP_S(kt + 3, 3, 2);
  }
  VMW(8); BAR(); STAGE_T(15, 3); COMPUTE(acc1, 0);  // step 12
  VMW(8); BAR(); COMPUTE(acc1, 1);                  // step 13
  VMW(4); BAR(); COMPUTE(acc1, 2);                  // step 14
  VMW(0); BAR(); COMPUTE(acc1, 3);                  // step 15

  // ---- hier GEMM (bf16): K=128 = 2 steps of BK=64; bufs 0,1 free ----
  STAGE_H(0, 0);
  STAGE_H(1, 1);
  VMW(4); BAR();
  COMPUTE_H(acc2, 0);
  VMW(0); BAR();
  COMPUTE_H(acc2, 1);
  __syncthreads();  // done reading before epilogue overwrites smem

  // ---- epilogue ----
  float* ss_l = (float*)smem;            // [128][36] padded (18432B)
  float* ex_l = (float*)(smem + 18432);  // [128][36]
  float* cm_l = (float*)(smem + 36864);  // [128]
  float* pr_l = (float*)(smem + 37376);  // [128]
  for (int i = t; i < 4096; i += 512) {
    int r = i >> 5, l = i & 31;
    ss_l[r * 36 + l] = ssb[(size_t)(brow + r) * 32 + l];
    ex_l[r * 36 + l] = expd[(size_t)(bcol + r) * 32 + l];
  }
  if (t < 128) cm_l[t] = cm[brow + t];
  else if (t < 256) pr_l[t - 128] = (bcol + t - 128 < C_DIM) ? proto[bcol + t - 128] : 0.f;
  __syncthreads();

  const int col0 = wn * 32 + l15;
  const int row0 = wm * 64 + (gq << 2);
#pragma unroll
  for (int m = 0; m < 4; ++m) {
    float ssum[4][2];
#pragma unroll
    for (int j = 0; j < 4; ++j)
#pragma unroll
      for (int n = 0; n < 2; ++n) ssum[j][n] = 0.f;
#pragma unroll
    for (int l4 = 0; l4 < 32; l4 += 4) {
      f32x4 evv[2], sv[4];
#pragma unroll
      for (int n = 0; n < 2; ++n)
        evv[n] = *(const f32x4*)&ex_l[(col0 + n * 16) * 36 + l4];
#pragma unroll
      for (int j = 0; j < 4; ++j)
        sv[j] = *(const f32x4*)&ss_l[(row0 + m * 16 + j) * 36 + l4];
#pragma unroll
      for (int j = 0; j < 4; ++j)
#pragma unroll
        for (int n = 0; n < 2; ++n) {
          ssum[j][n] += fabsf(sv[j][0] - evv[n][0]) + fabsf(sv[j][1] - evv[n][1]) +
                        fabsf(sv[j][2] - evv[n][2]) + fabsf(sv[j][3] - evv[n][3]);
        }
    }
#pragma unroll
    for (int j = 0; j < 4; ++j) {
      int rloc = row0 + m * 16 + j;
      float cmv = cm_l[rloc];
#pragma unroll
      for (int n = 0; n < 2; ++n) {
        int cloc = col0 + n * 16;
        int cg = bcol + cloc;
        // acc1 carries the x32 wsig scale: triadic = 0.5 + 0.5*acc/32
        float tria = fminf(fmaxf(0.5f + acc1[m][n][j] * 0.015625f, EPS), 1.0f);
        float hier = fminf(fmaxf(0.5f + 0.25f * acc2[m][n][j], EPS), 1.0f);
        float sc = fminf(fmaxf(1.0f - ssum[j][n] * (1.0f / 31.0f), EPS), 1.0f);
        float d = cmv - pr_l[cloc];
        float cc = __expf(d * d * -10.0f) + 1e-8f;
        cc = fminf(fmaxf(cc, EPS), 1.0f);
        float p = tria * sc * cc * hier;
        if (cg < C_DIM)
          out[(size_t)(brow + rloc) * C_DIM + cg] = sqrtf(sqrtf(p));
      }
    }
  }
}

extern "C" void kernel_launch(void* const* d_in, const int* in_sizes, int n_in,
                              void* d_out, int out_size, void* d_ws, size_t ws_size,
                              hipStream_t stream) {
  (void)in_sizes; (void)n_in; (void)out_size; (void)ws_size;
  const float* pe = (const float*)d_in[0];     // B x L x F
  const float* cm = (const float*)d_in[1];     // B
  const float* sig = (const float*)d_in[2];    // C x L x F
  const float* proto = (const float*)d_in[3];  // C
  const float* lr = (const float*)d_in[4];     // C x L
  float* out = (float*)d_out;
  char* ws = (char*)d_ws;

  __hip_fp8_e4m3* wsig = (__hip_fp8_e4m3*)(ws);               // CP*2048 = 2 MiB
  __hip_fp8_e4m3* pen = (__hip_fp8_e4m3*)(ws + 2097152);      // B*2048  = 8 MiB
  __hip_bfloat16* elb = (__hip_bfloat16*)(ws + 10485760);     // B*128*2 = 1 MiB
  __hip_bfloat16* elc = (__hip_bfloat16*)(ws + 11534336);     // CP*128*2 = 256 KiB
  float* ssb = (float*)(ws + 11796480);                       // B*32*4  = 512 KiB
  float* expd = (float*)(ws + 12320768);                      // CP*32*4 = 128 KiB

  prep_all<<<(CP + B_DIM) / 4, 256, 0, stream>>>(sig, lr, pe, wsig, expd, elc, pen, ssb, elb);
  dim3 grid(B_DIM / 128, CP / 128);
  basin_main<<<grid, 512, 0, stream>>>((const unsigned char*)pen, (const unsigned char*)wsig,
                                       elb, elc, ssb, expd, cm, proto, out);
}